// Round 2
// baseline (852.283 us; speedup 1.0000x reference)
//
#include <hip/hip_runtime.h>
#include <math.h>

#define TPB    256
#define CHUNK  1024
#define DHEAD  128
#define NB     8      // batch
#define NJ     4      // output columns per block in out_proj
#define PSTRIDE (DHEAD + 2)

// ---------------------------------------------------------------------------
// Kernel 1: per-(b,h,split) flash-decode partial + fused last-block combine.
//   Pass 1: scores for CHUNK keys into LDS (coalesced float4 K reads,
//           32-lane shuffle dot-reduce, 2 rows in flight per group).
//   Pass 2: chunk softmax (m, l) + P.V with float4 V reads.
//   Emits unnormalized acc[128], m, l to workspace; the LAST block to finish
//   for a given (b,h) performs the log-sum-exp merge and writes attn.
// ---------------------------------------------------------------------------
__global__ __launch_bounds__(TPB) void attn_partial(
    const float* __restrict__ q, const float* __restrict__ kc,
    const float* __restrict__ vc, float* __restrict__ part,
    float* __restrict__ attn, unsigned int* __restrict__ cnt,
    int S, int nsplit)
{
    const int bh    = blockIdx.x;     // b*H + h
    const int split = blockIdx.y;
    const int tid   = threadIdx.x;
    const int s0    = split * CHUNK;

    __shared__ float sc[CHUNK];          // 4 KB scores
    __shared__ float qs[DHEAD];          // 512 B
    __shared__ float red[8];             // reduce scratch
    __shared__ float accs[8][DHEAD];     // 4 KB PV group partials
    __shared__ unsigned int done_prev;

    if (tid < DHEAD) qs[tid] = q[(size_t)bh * DHEAD + tid];
    __syncthreads();

    const int lane32 = tid & 31;         // float4 slot within a row (32*4=128)
    const int grp    = tid >> 5;         // 0..7
    const float4 q4  = ((const float4*)qs)[lane32];
    const float scale = 0.088388347648318447f;  // 1/sqrt(128)

    // ---- pass 1: scores (2 rows per group per iteration: 2 loads in flight)
    const float* Kbase = kc + ((size_t)bh * S + s0) * DHEAD;
    for (int it = 0; it < CHUNK / 16; ++it) {
        const int r0 = it * 16 + grp;
        const int r1 = r0 + 8;
        const float4 ka = ((const float4*)(Kbase + (size_t)r0 * DHEAD))[lane32];
        const float4 kb = ((const float4*)(Kbase + (size_t)r1 * DHEAD))[lane32];
        float pa = q4.x * ka.x + q4.y * ka.y + q4.z * ka.z + q4.w * ka.w;
        float pb = q4.x * kb.x + q4.y * kb.y + q4.z * kb.z + q4.w * kb.w;
        #pragma unroll
        for (int off = 16; off > 0; off >>= 1) {
            pa += __shfl_xor(pa, off);
            pb += __shfl_xor(pb, off);
        }
        if (lane32 == 0) { sc[r0] = pa * scale; sc[r1] = pb * scale; }
    }
    __syncthreads();

    // ---- chunk max ----
    float m = -INFINITY;
    for (int i = tid; i < CHUNK; i += TPB) m = fmaxf(m, sc[i]);
    #pragma unroll
    for (int off = 32; off > 0; off >>= 1) m = fmaxf(m, __shfl_xor(m, off));
    if ((tid & 63) == 0) red[tid >> 6] = m;
    __syncthreads();
    m = fmaxf(fmaxf(red[0], red[1]), fmaxf(red[2], red[3]));

    // ---- exp + sum (writes sc in place) ----
    float lsum = 0.f;
    for (int i = tid; i < CHUNK; i += TPB) {
        const float e = expf(sc[i] - m);
        sc[i] = e;
        lsum += e;
    }
    #pragma unroll
    for (int off = 32; off > 0; off >>= 1) lsum += __shfl_xor(lsum, off);
    if ((tid & 63) == 0) red[4 + (tid >> 6)] = lsum;
    __syncthreads();                      // also makes sc[] writes visible
    lsum = red[4] + red[5] + red[6] + red[7];

    // ---- pass 2: P.V. group g owns s in [g*128, (g+1)*128), lanes own 4 cols
    const float* Vbase = vc + ((size_t)bh * S + s0) * DHEAD;
    float4 acc = make_float4(0.f, 0.f, 0.f, 0.f);
    const int sBeg = grp * (CHUNK / 8);
    for (int s = sBeg; s < sBeg + CHUNK / 8; ++s) {
        const float  p  = sc[s];          // LDS broadcast within 32-lane group
        const float4 v4 = ((const float4*)(Vbase + (size_t)s * DHEAD))[lane32];
        acc.x += p * v4.x; acc.y += p * v4.y;
        acc.z += p * v4.z; acc.w += p * v4.w;
    }
    ((float4*)accs[grp])[lane32] = acc;
    __syncthreads();

    float* P = part + ((size_t)bh * nsplit + split) * PSTRIDE;
    if (tid < DHEAD) {
        float a = 0.f;
        #pragma unroll
        for (int g = 0; g < 8; ++g) a += accs[g][tid];
        P[tid] = a;
    }
    if (tid == 0) { P[DHEAD] = m; P[DHEAD + 1] = lsum; }

    // ---- last-block-per-bh combine (split-K pattern) ----
    __threadfence();                      // make this block's P writes device-visible
    __syncthreads();                      // all threads' fences done
    if (tid == 0) {
        done_prev = __hip_atomic_fetch_add(&cnt[bh], 1u, __ATOMIC_ACQ_REL,
                                           __HIP_MEMORY_SCOPE_AGENT);
    }
    __syncthreads();
    if (done_prev == (unsigned)(nsplit - 1)) {
        if (tid < DHEAD) {
            const float* Pb = part + (size_t)bh * nsplit * PSTRIDE;
            float gm = -INFINITY;
            for (int s = 0; s < nsplit; ++s) {
                const float ms = __hip_atomic_load(Pb + s * PSTRIDE + DHEAD,
                                                   __ATOMIC_RELAXED,
                                                   __HIP_MEMORY_SCOPE_AGENT);
                gm = fmaxf(gm, ms);
            }
            float l = 0.f, a = 0.f;
            for (int s = 0; s < nsplit; ++s) {
                const float ms = __hip_atomic_load(Pb + s * PSTRIDE + DHEAD,
                                                   __ATOMIC_RELAXED,
                                                   __HIP_MEMORY_SCOPE_AGENT);
                const float ls = __hip_atomic_load(Pb + s * PSTRIDE + DHEAD + 1,
                                                   __ATOMIC_RELAXED,
                                                   __HIP_MEMORY_SCOPE_AGENT);
                const float as = __hip_atomic_load(Pb + s * PSTRIDE + tid,
                                                   __ATOMIC_RELAXED,
                                                   __HIP_MEMORY_SCOPE_AGENT);
                const float w = expf(ms - gm);
                l += ls * w;
                a += as * w;
            }
            attn[(size_t)bh * DHEAD + tid] = a / l;  // bh*128 == b*(H*D)+h*D
        }
    }
}

// ---------------------------------------------------------------------------
// Kernel 2: out[b][j] = bias[j] + attn[b,:] . W[j,:]   (torch Linear: x @ W^T)
// NJ=4 columns per block: W rows streamed once (64 MB total), attn loads
// amortized 4x, 16-deep i-loop for latency hiding.
// ---------------------------------------------------------------------------
__global__ __launch_bounds__(TPB) void out_proj(
    const float* __restrict__ attn, const float* __restrict__ W,
    const float* __restrict__ bias, float* __restrict__ out, int HD)
{
    const int j0  = blockIdx.x * NJ;
    const int tid = threadIdx.x;
    const int nv  = HD >> 2;             // 1024 float4s per row
    const float4* attn4 = (const float4*)attn;

    float acc[NJ][NB];
    #pragma unroll
    for (int c = 0; c < NJ; ++c)
        #pragma unroll
        for (int b = 0; b < NB; ++b) acc[c][b] = 0.f;

    for (int i = tid; i < nv; i += TPB) {           // 4 iterations
        float4 w4[NJ];
        #pragma unroll
        for (int c = 0; c < NJ; ++c)
            w4[c] = ((const float4*)(W + (size_t)(j0 + c) * HD))[i];
        #pragma unroll
        for (int b = 0; b < NB; ++b) {
            const float4 a4 = attn4[(size_t)b * nv + i];
            #pragma unroll
            for (int c = 0; c < NJ; ++c) {
                acc[c][b] += w4[c].x * a4.x + w4[c].y * a4.y
                           + w4[c].z * a4.z + w4[c].w * a4.w;
            }
        }
    }

    // wave-level reduce (64 lanes), then cross-wave via LDS
    #pragma unroll
    for (int c = 0; c < NJ; ++c)
        #pragma unroll
        for (int b = 0; b < NB; ++b)
            #pragma unroll
            for (int off = 32; off > 0; off >>= 1)
                acc[c][b] += __shfl_xor(acc[c][b], off);

    __shared__ float red[4][NJ][NB];
    if ((tid & 63) == 0) {
        #pragma unroll
        for (int c = 0; c < NJ; ++c)
            #pragma unroll
            for (int b = 0; b < NB; ++b) red[tid >> 6][c][b] = acc[c][b];
    }
    __syncthreads();
    if (tid < NJ * NB) {
        const int c = tid >> 3, b = tid & 7;
        const float r = red[0][c][b] + red[1][c][b] + red[2][c][b] + red[3][c][b];
        out[(size_t)b * HD + (j0 + c)] = r + bias[j0 + c];
    }
}

// ---------------------------------------------------------------------------
extern "C" void kernel_launch(void* const* d_in, const int* in_sizes, int n_in,
                              void* d_out, int out_size, void* d_ws, size_t ws_size,
                              hipStream_t stream)
{
    const float* q    = (const float*)d_in[0];
    const float* kc   = (const float*)d_in[1];
    const float* vc   = (const float*)d_in[2];
    const float* W    = (const float*)d_in[3];
    const float* bias = (const float*)d_in[4];
    float* out = (float*)d_out;

    const int HD = in_sizes[4];                 // H*D = 4096
    const int B  = in_sizes[0] / HD;            // 8
    const int H  = HD / DHEAD;                  // 32
    const int S  = in_sizes[1] / in_sizes[0];   // 8192
    const int BH = B * H;                       // 256
    const int nsplit = S / CHUNK;               // 8

    float* part = (float*)d_ws;                              // BH*nsplit*130 floats
    float* attn = part + (size_t)BH * nsplit * PSTRIDE;      // B*HD floats (128 KB)
    unsigned int* cnt = (unsigned int*)(attn + (size_t)B * HD);  // BH counters

    hipMemsetAsync(cnt, 0, (size_t)BH * sizeof(unsigned int), stream);
    attn_partial<<<dim3(BH, nsplit), TPB, 0, stream>>>(q, kc, vc, part, attn, cnt,
                                                       S, nsplit);
    out_proj<<<HD / NJ, TPB, 0, stream>>>(attn, W, bias, out, HD);
}

// Round 3
// 395.426 us; speedup vs baseline: 2.1554x; 2.1554x over previous
//
#include <hip/hip_runtime.h>
#include <math.h>

#define TPB    256
#define CHUNK  1024
#define DHEAD  128
#define NB     8      // batch
#define NJ     4      // output columns per block in out_proj
#define PSTRIDE (DHEAD + 2)

// ---------------------------------------------------------------------------
// Kernel 1: per-(b,h,split) flash-decode partial. NO device-scope fences —
// round 2 showed per-block __threadfence/agent-atomics cause L2
// writeback/invalidate storms that collapse streaming BW to 15% of peak.
//   Pass 1: scores for CHUNK keys into LDS (coalesced float4 K reads,
//           32-lane shuffle dot-reduce, 2 rows in flight per group).
//   Pass 2: chunk softmax (m, l) + P.V with float4 V reads, 2 loads in flight.
//   Emits unnormalized acc[128], m, l to workspace.
// ---------------------------------------------------------------------------
__global__ __launch_bounds__(TPB) void attn_partial(
    const float* __restrict__ q, const float* __restrict__ kc,
    const float* __restrict__ vc, float* __restrict__ part,
    int S, int nsplit)
{
    const int bh    = blockIdx.x;     // b*H + h
    const int split = blockIdx.y;
    const int tid   = threadIdx.x;
    const int s0    = split * CHUNK;

    __shared__ float sc[CHUNK];          // 4 KB scores
    __shared__ float red[8];             // reduce scratch
    __shared__ float accs[8][DHEAD];     // 4 KB PV group partials

    const int lane32 = tid & 31;         // float4 slot within a row (32*4=128)
    const int grp    = tid >> 5;         // 0..7
    // broadcast q load straight from global (L1/L2-served, saves a barrier)
    const float4 q4 = ((const float4*)(q + (size_t)bh * DHEAD))[lane32];
    const float scale = 0.088388347648318447f;  // 1/sqrt(128)

    // ---- pass 1: scores (2 rows per group per iteration: 2 loads in flight)
    const float* Kbase = kc + ((size_t)bh * S + s0) * DHEAD;
    for (int it = 0; it < CHUNK / 16; ++it) {
        const int r0 = it * 16 + grp;
        const int r1 = r0 + 8;
        const float4 ka = ((const float4*)(Kbase + (size_t)r0 * DHEAD))[lane32];
        const float4 kb = ((const float4*)(Kbase + (size_t)r1 * DHEAD))[lane32];
        float pa = q4.x * ka.x + q4.y * ka.y + q4.z * ka.z + q4.w * ka.w;
        float pb = q4.x * kb.x + q4.y * kb.y + q4.z * kb.z + q4.w * kb.w;
        #pragma unroll
        for (int off = 16; off > 0; off >>= 1) {
            pa += __shfl_xor(pa, off);
            pb += __shfl_xor(pb, off);
        }
        if (lane32 == 0) { sc[r0] = pa * scale; sc[r1] = pb * scale; }
    }
    __syncthreads();

    // ---- chunk max ----
    float m = -INFINITY;
    for (int i = tid; i < CHUNK; i += TPB) m = fmaxf(m, sc[i]);
    #pragma unroll
    for (int off = 32; off > 0; off >>= 1) m = fmaxf(m, __shfl_xor(m, off));
    if ((tid & 63) == 0) red[tid >> 6] = m;
    __syncthreads();
    m = fmaxf(fmaxf(red[0], red[1]), fmaxf(red[2], red[3]));

    // ---- exp + sum (writes sc in place) ----
    float lsum = 0.f;
    for (int i = tid; i < CHUNK; i += TPB) {
        const float e = expf(sc[i] - m);
        sc[i] = e;
        lsum += e;
    }
    #pragma unroll
    for (int off = 32; off > 0; off >>= 1) lsum += __shfl_xor(lsum, off);
    if ((tid & 63) == 0) red[4 + (tid >> 6)] = lsum;
    __syncthreads();                      // also makes sc[] writes visible
    lsum = red[4] + red[5] + red[6] + red[7];

    // ---- pass 2: P.V. group g owns s in [g*128, (g+1)*128), lanes own 4 cols
    const float* Vbase = vc + ((size_t)bh * S + s0) * DHEAD;
    float4 acc = make_float4(0.f, 0.f, 0.f, 0.f);
    const int sBeg = grp * (CHUNK / 8);
    for (int s = sBeg; s < sBeg + CHUNK / 8; s += 2) {
        const float  p0 = sc[s];
        const float  p1 = sc[s + 1];
        const float4 v0 = ((const float4*)(Vbase + (size_t)s * DHEAD))[lane32];
        const float4 v1 = ((const float4*)(Vbase + (size_t)(s + 1) * DHEAD))[lane32];
        acc.x += p0 * v0.x + p1 * v1.x;
        acc.y += p0 * v0.y + p1 * v1.y;
        acc.z += p0 * v0.z + p1 * v1.z;
        acc.w += p0 * v0.w + p1 * v1.w;
    }
    ((float4*)accs[grp])[lane32] = acc;
    __syncthreads();

    float* P = part + ((size_t)bh * nsplit + split) * PSTRIDE;
    if (tid < DHEAD) {
        float a = 0.f;
        #pragma unroll
        for (int g = 0; g < 8; ++g) a += accs[g][tid];
        P[tid] = a;
    }
    if (tid == 0) { P[DHEAD] = m; P[DHEAD + 1] = lsum; }
}

// ---------------------------------------------------------------------------
// Kernel 2: combine splits (log-sum-exp merge), write attn as [B, H*D].
// ---------------------------------------------------------------------------
__global__ __launch_bounds__(DHEAD) void attn_combine(
    const float* __restrict__ part, float* __restrict__ attn,
    int nsplit)
{
    const int bh  = blockIdx.x;
    const int tid = threadIdx.x;        // 0..127
    const float* P = part + (size_t)bh * nsplit * PSTRIDE;

    float m = -INFINITY;
    for (int s = 0; s < nsplit; ++s)
        m = fmaxf(m, P[s * PSTRIDE + DHEAD]);

    float l = 0.f, a = 0.f;
    for (int s = 0; s < nsplit; ++s) {
        const float w = expf(P[s * PSTRIDE + DHEAD] - m);
        l += P[s * PSTRIDE + DHEAD + 1] * w;
        a += P[s * PSTRIDE + tid] * w;
    }
    attn[(size_t)bh * DHEAD + tid] = a / l;   // bh*128 == b*(H*D) + h*D
}

// ---------------------------------------------------------------------------
// Kernel 3: out[b][j] = bias[j] + attn[b,:] . W[j,:]   (torch Linear: x @ W^T)
// NJ=4 columns per block: W rows streamed once (64 MB total), attn loads
// amortized 4x, 16-deep load pipeline per i-iteration.
// ---------------------------------------------------------------------------
__global__ __launch_bounds__(TPB) void out_proj(
    const float* __restrict__ attn, const float* __restrict__ W,
    const float* __restrict__ bias, float* __restrict__ out, int HD)
{
    const int j0  = blockIdx.x * NJ;
    const int tid = threadIdx.x;
    const int nv  = HD >> 2;             // 1024 float4s per row
    const float4* attn4 = (const float4*)attn;

    float acc[NJ][NB];
    #pragma unroll
    for (int c = 0; c < NJ; ++c)
        #pragma unroll
        for (int b = 0; b < NB; ++b) acc[c][b] = 0.f;

    for (int i = tid; i < nv; i += TPB) {           // 4 iterations
        float4 w4[NJ];
        #pragma unroll
        for (int c = 0; c < NJ; ++c)
            w4[c] = ((const float4*)(W + (size_t)(j0 + c) * HD))[i];
        #pragma unroll
        for (int b = 0; b < NB; ++b) {
            const float4 a4 = attn4[(size_t)b * nv + i];
            #pragma unroll
            for (int c = 0; c < NJ; ++c) {
                acc[c][b] += w4[c].x * a4.x + w4[c].y * a4.y
                           + w4[c].z * a4.z + w4[c].w * a4.w;
            }
        }
    }

    // wave-level reduce (64 lanes), then cross-wave via LDS
    #pragma unroll
    for (int c = 0; c < NJ; ++c)
        #pragma unroll
        for (int b = 0; b < NB; ++b)
            #pragma unroll
            for (int off = 32; off > 0; off >>= 1)
                acc[c][b] += __shfl_xor(acc[c][b], off);

    __shared__ float red[4][NJ][NB];
    if ((tid & 63) == 0) {
        #pragma unroll
        for (int c = 0; c < NJ; ++c)
            #pragma unroll
            for (int b = 0; b < NB; ++b) red[tid >> 6][c][b] = acc[c][b];
    }
    __syncthreads();
    if (tid < NJ * NB) {
        const int c = tid >> 3, b = tid & 7;
        const float r = red[0][c][b] + red[1][c][b] + red[2][c][b] + red[3][c][b];
        out[(size_t)b * HD + (j0 + c)] = r + bias[j0 + c];
    }
}

// ---------------------------------------------------------------------------
extern "C" void kernel_launch(void* const* d_in, const int* in_sizes, int n_in,
                              void* d_out, int out_size, void* d_ws, size_t ws_size,
                              hipStream_t stream)
{
    const float* q    = (const float*)d_in[0];
    const float* kc   = (const float*)d_in[1];
    const float* vc   = (const float*)d_in[2];
    const float* W    = (const float*)d_in[3];
    const float* bias = (const float*)d_in[4];
    float* out = (float*)d_out;

    const int HD = in_sizes[4];                 // H*D = 4096
    const int B  = in_sizes[0] / HD;            // 8
    const int S  = in_sizes[1] / in_sizes[0];   // 8192
    const int BH = in_sizes[0] / DHEAD;         // B*H = 256
    const int nsplit = S / CHUNK;               // 8

    float* part = (float*)d_ws;                              // BH*nsplit*130 floats
    float* attn = part + (size_t)BH * nsplit * PSTRIDE;      // B*HD floats (128 KB)

    attn_partial<<<dim3(BH, nsplit), TPB, 0, stream>>>(q, kc, vc, part, S, nsplit);
    attn_combine<<<BH, DHEAD, 0, stream>>>(part, attn, nsplit);
    out_proj<<<HD / NJ, TPB, 0, stream>>>(attn, W, bias, out, HD);
}

// Round 4
// 392.787 us; speedup vs baseline: 2.1698x; 1.0067x over previous
//
#include <hip/hip_runtime.h>
#include <math.h>

#define TPB    256
#define CHUNK  1024
#define DHEAD  128
#define NB     8      // batch
#define NJ     8      // output columns per block in out_proj
#define PSTRIDE (DHEAD + 2)

// ---------------------------------------------------------------------------
// Kernel 1: per-(b,h,split) flash-decode partial. 2 barriers, 1 LDS sweep.
//   Pass 1: scores -> LDS; chunk max tracked IN REGISTERS (butterfly leaves
//           the dot in all 32 lanes, so max folding is free per lane).
//   Pass 2: PV with exp fused in (redundant per-lane __expf, hidden under
//           the V stream); lsum accumulated inline.
//   NO device-scope fences (round-2 lesson: they collapse streaming BW).
// ---------------------------------------------------------------------------
__global__ __launch_bounds__(TPB) void attn_partial(
    const float* __restrict__ q, const float* __restrict__ kc,
    const float* __restrict__ vc, float* __restrict__ part,
    int S, int nsplit)
{
    const int bh    = blockIdx.x;     // b*H + h
    const int split = blockIdx.y;
    const int tid   = threadIdx.x;
    const int s0    = split * CHUNK;

    __shared__ float sc[CHUNK];          // 4 KB scores
    __shared__ float redm[4];            // per-wave max
    __shared__ float redl[8];            // per-group lsum
    __shared__ float accs[8][DHEAD];     // 4 KB PV group partials

    const int lane32 = tid & 31;         // float4 slot within a row (32*4=128)
    const int grp    = tid >> 5;         // 0..7
    const float4 q4 = ((const float4*)(q + (size_t)bh * DHEAD))[lane32];
    const float scale = 0.088388347648318447f;  // 1/sqrt(128)

    // ---- pass 1: scores (2 rows per group per iter) + register max ----
    const float* Kbase = kc + ((size_t)bh * S + s0) * DHEAD;
    float mloc = -INFINITY;
    for (int it = 0; it < CHUNK / 16; ++it) {
        const int r0 = it * 16 + grp;
        const int r1 = r0 + 8;
        const float4 ka = ((const float4*)(Kbase + (size_t)r0 * DHEAD))[lane32];
        const float4 kb = ((const float4*)(Kbase + (size_t)r1 * DHEAD))[lane32];
        float pa = q4.x * ka.x + q4.y * ka.y + q4.z * ka.z + q4.w * ka.w;
        float pb = q4.x * kb.x + q4.y * kb.y + q4.z * kb.z + q4.w * kb.w;
        #pragma unroll
        for (int off = 16; off > 0; off >>= 1) {
            pa += __shfl_xor(pa, off);
            pb += __shfl_xor(pb, off);
        }
        pa *= scale; pb *= scale;
        mloc = fmaxf(mloc, fmaxf(pa, pb));   // all 32 lanes hold full dots
        if (lane32 == 0) { sc[r0] = pa; sc[r1] = pb; }
    }
    // cross-group (within wave) then cross-wave max
    mloc = fmaxf(mloc, __shfl_xor(mloc, 32));
    if ((tid & 63) == 0) redm[tid >> 6] = mloc;
    __syncthreads();                      // covers sc[] writes + redm
    const float m = fmaxf(fmaxf(redm[0], redm[1]), fmaxf(redm[2], redm[3]));

    // ---- pass 2: PV with fused exp + lsum. group g owns rows
    //      [g*128,(g+1)*128), lanes own 4 columns each.
    const float* Vbase = vc + ((size_t)bh * S + s0) * DHEAD;
    float4 acc = make_float4(0.f, 0.f, 0.f, 0.f);
    float lsum = 0.f;
    const int sBeg = grp * (CHUNK / 8);
    for (int s = sBeg; s < sBeg + CHUNK / 8; s += 2) {
        const float4 v0 = ((const float4*)(Vbase + (size_t)s * DHEAD))[lane32];
        const float4 v1 = ((const float4*)(Vbase + (size_t)(s + 1) * DHEAD))[lane32];
        const float p0 = __expf(sc[s] - m);       // uniform within group
        const float p1 = __expf(sc[s + 1] - m);
        acc.x += p0 * v0.x + p1 * v1.x;
        acc.y += p0 * v0.y + p1 * v1.y;
        acc.z += p0 * v0.z + p1 * v1.z;
        acc.w += p0 * v0.w + p1 * v1.w;
        lsum += p0 + p1;
    }
    ((float4*)accs[grp])[lane32] = acc;
    if (lane32 == 0) redl[grp] = lsum;   // lsum uniform within group
    __syncthreads();

    float* P = part + ((size_t)bh * nsplit + split) * PSTRIDE;
    if (tid < DHEAD) {
        float a = 0.f;
        #pragma unroll
        for (int g = 0; g < 8; ++g) a += accs[g][tid];
        P[tid] = a;
    }
    if (tid == 0) {
        P[DHEAD] = m;
        P[DHEAD + 1] = ((redl[0] + redl[1]) + (redl[2] + redl[3]))
                     + ((redl[4] + redl[5]) + (redl[6] + redl[7]));
    }
}

// ---------------------------------------------------------------------------
// Kernel 2: combine splits (log-sum-exp merge), write attn as [B, H*D].
// ---------------------------------------------------------------------------
__global__ __launch_bounds__(DHEAD) void attn_combine(
    const float* __restrict__ part, float* __restrict__ attn,
    int nsplit)
{
    const int bh  = blockIdx.x;
    const int tid = threadIdx.x;        // 0..127
    const float* P = part + (size_t)bh * nsplit * PSTRIDE;

    float m = -INFINITY;
    for (int s = 0; s < nsplit; ++s)
        m = fmaxf(m, P[s * PSTRIDE + DHEAD]);

    float l = 0.f, a = 0.f;
    for (int s = 0; s < nsplit; ++s) {
        const float w = __expf(P[s * PSTRIDE + DHEAD] - m);
        l += P[s * PSTRIDE + DHEAD + 1] * w;
        a += P[s * PSTRIDE + tid] * w;
    }
    attn[(size_t)bh * DHEAD + tid] = a / l;   // bh*128 == b*(H*D) + h*D
}

// ---------------------------------------------------------------------------
// Kernel 3: out[b][j] = bias[j] + attn[b,:] . W[j,:]   (torch Linear: x @ W^T)
// NJ=8 columns per block: W rows streamed once (64 MB total), attn L2 reads
// amortized 8x, 8-deep i-loop for latency hiding.
// ---------------------------------------------------------------------------
__global__ __launch_bounds__(TPB) void out_proj(
    const float* __restrict__ attn, const float* __restrict__ W,
    const float* __restrict__ bias, float* __restrict__ out, int HD)
{
    const int j0  = blockIdx.x * NJ;
    const int tid = threadIdx.x;
    const int nv  = HD >> 2;             // 1024 float4s per row
    const float4* attn4 = (const float4*)attn;

    float acc[NJ][NB];
    #pragma unroll
    for (int c = 0; c < NJ; ++c)
        #pragma unroll
        for (int b = 0; b < NB; ++b) acc[c][b] = 0.f;

    for (int i = tid; i < nv; i += TPB) {           // 4 iterations
        float4 w4[NJ];
        #pragma unroll
        for (int c = 0; c < NJ; ++c)
            w4[c] = ((const float4*)(W + (size_t)(j0 + c) * HD))[i];
        #pragma unroll
        for (int b = 0; b < NB; ++b) {
            const float4 a4 = attn4[(size_t)b * nv + i];
            #pragma unroll
            for (int c = 0; c < NJ; ++c) {
                acc[c][b] += w4[c].x * a4.x + w4[c].y * a4.y
                           + w4[c].z * a4.z + w4[c].w * a4.w;
            }
        }
    }

    // wave-level reduce (64 lanes), then cross-wave via LDS
    #pragma unroll
    for (int c = 0; c < NJ; ++c)
        #pragma unroll
        for (int b = 0; b < NB; ++b)
            #pragma unroll
            for (int off = 32; off > 0; off >>= 1)
                acc[c][b] += __shfl_xor(acc[c][b], off);

    __shared__ float red[4][NJ][NB];
    if ((tid & 63) == 0) {
        #pragma unroll
        for (int c = 0; c < NJ; ++c)
            #pragma unroll
            for (int b = 0; b < NB; ++b) red[tid >> 6][c][b] = acc[c][b];
    }
    __syncthreads();
    if (tid < NJ * NB) {                 // 64 threads
        const int c = tid >> 3, b = tid & 7;
        const float r = red[0][c][b] + red[1][c][b] + red[2][c][b] + red[3][c][b];
        out[(size_t)b * HD + (j0 + c)] = r + bias[j0 + c];
    }
}

// ---------------------------------------------------------------------------
extern "C" void kernel_launch(void* const* d_in, const int* in_sizes, int n_in,
                              void* d_out, int out_size, void* d_ws, size_t ws_size,
                              hipStream_t stream)
{
    const float* q    = (const float*)d_in[0];
    const float* kc   = (const float*)d_in[1];
    const float* vc   = (const float*)d_in[2];
    const float* W    = (const float*)d_in[3];
    const float* bias = (const float*)d_in[4];
    float* out = (float*)d_out;

    const int HD = in_sizes[4];                 // H*D = 4096
    const int S  = in_sizes[1] / in_sizes[0];   // 8192
    const int BH = in_sizes[0] / DHEAD;         // B*H = 256
    const int nsplit = S / CHUNK;               // 8

    float* part = (float*)d_ws;                              // BH*nsplit*130 floats
    float* attn = part + (size_t)BH * nsplit * PSTRIDE;      // B*HD floats (128 KB)

    attn_partial<<<dim3(BH, nsplit), TPB, 0, stream>>>(q, kc, vc, part, S, nsplit);
    attn_combine<<<BH, DHEAD, 0, stream>>>(part, attn, nsplit);
    out_proj<<<HD / NJ, TPB, 0, stream>>>(attn, W, bias, out, HD);
}

// Round 6
// 348.787 us; speedup vs baseline: 2.4436x; 1.1262x over previous
//
#include <hip/hip_runtime.h>
#include <math.h>

#define TPB    256
#define CHUNK  1024
#define DHEAD  128
#define NB     8      // batch
#define NJ     8      // output columns per block in out_proj
#define PSTRIDE (DHEAD + 2)

// native vector type for __builtin_nontemporal_load (HIP float4 is a struct)
typedef float f4 __attribute__((ext_vector_type(4)));

__device__ __forceinline__ f4 nt_load4(const float* p) {
    return __builtin_nontemporal_load((const f4*)p);
}

// ---------------------------------------------------------------------------
// Kernel 1: per-(b,h,split) flash-decode partial. 2 barriers, 1 LDS sweep.
//   Pass 1: scores -> LDS, 4 K-rows in flight per group, register max.
//   Pass 2: PV with fused exp + lsum, 4 V-rows in flight.
//   K/V via nontemporal loads (streamed exactly once, no reuse).
//   NO device-scope fences (round-2 lesson: L2 flush storms kill BW).
// ---------------------------------------------------------------------------
__global__ __launch_bounds__(TPB) void attn_partial(
    const float* __restrict__ q, const float* __restrict__ kc,
    const float* __restrict__ vc, float* __restrict__ part,
    int S, int nsplit)
{
    const int bh    = blockIdx.x;     // b*H + h
    const int split = blockIdx.y;
    const int tid   = threadIdx.x;
    const int s0    = split * CHUNK;

    __shared__ float sc[CHUNK];          // 4 KB scores
    __shared__ float redm[4];            // per-wave max
    __shared__ float redl[8];            // per-group lsum
    __shared__ float accs[8][DHEAD];     // 4 KB PV group partials

    const int lane32 = tid & 31;         // float4 slot within a row (32*4=128)
    const int grp    = tid >> 5;         // 0..7
    const f4 q4 = *((const f4*)(q + (size_t)bh * DHEAD) + lane32);
    const float scale = 0.088388347648318447f;  // 1/sqrt(128)

    // ---- pass 1: scores, 4 rows per group per iter (4 loads in flight) ----
    const float* Kbase = kc + ((size_t)bh * S + s0) * DHEAD;
    float mloc = -INFINITY;
    for (int it = 0; it < CHUNK / 32; ++it) {
        const int r0 = it * 32 + grp;
        const f4 ka = nt_load4(Kbase + (size_t)(r0     ) * DHEAD + lane32 * 4);
        const f4 kb = nt_load4(Kbase + (size_t)(r0 +  8) * DHEAD + lane32 * 4);
        const f4 kx = nt_load4(Kbase + (size_t)(r0 + 16) * DHEAD + lane32 * 4);
        const f4 kd = nt_load4(Kbase + (size_t)(r0 + 24) * DHEAD + lane32 * 4);
        float pa = q4.x * ka.x + q4.y * ka.y + q4.z * ka.z + q4.w * ka.w;
        float pb = q4.x * kb.x + q4.y * kb.y + q4.z * kb.z + q4.w * kb.w;
        float pc = q4.x * kx.x + q4.y * kx.y + q4.z * kx.z + q4.w * kx.w;
        float pd = q4.x * kd.x + q4.y * kd.y + q4.z * kd.z + q4.w * kd.w;
        #pragma unroll
        for (int off = 16; off > 0; off >>= 1) {   // 4-wide ILP butterfly
            pa += __shfl_xor(pa, off);
            pb += __shfl_xor(pb, off);
            pc += __shfl_xor(pc, off);
            pd += __shfl_xor(pd, off);
        }
        pa *= scale; pb *= scale; pc *= scale; pd *= scale;
        mloc = fmaxf(mloc, fmaxf(fmaxf(pa, pb), fmaxf(pc, pd)));
        if (lane32 == 0) {
            sc[r0] = pa; sc[r0 + 8] = pb; sc[r0 + 16] = pc; sc[r0 + 24] = pd;
        }
    }
    // cross-group (within wave) then cross-wave max
    mloc = fmaxf(mloc, __shfl_xor(mloc, 32));
    if ((tid & 63) == 0) redm[tid >> 6] = mloc;
    __syncthreads();                      // covers sc[] writes + redm
    const float m = fmaxf(fmaxf(redm[0], redm[1]), fmaxf(redm[2], redm[3]));

    // ---- pass 2: PV with fused exp + lsum, 4 loads in flight. group g owns
    //      rows [g*128,(g+1)*128), lanes own 4 columns each.
    const float* Vbase = vc + ((size_t)bh * S + s0) * DHEAD;
    f4 acc = (f4)(0.f);
    float lsum = 0.f;
    const int sBeg = grp * (CHUNK / 8);
    for (int s = sBeg; s < sBeg + CHUNK / 8; s += 4) {
        const f4 v0 = nt_load4(Vbase + (size_t)(s    ) * DHEAD + lane32 * 4);
        const f4 v1 = nt_load4(Vbase + (size_t)(s + 1) * DHEAD + lane32 * 4);
        const f4 v2 = nt_load4(Vbase + (size_t)(s + 2) * DHEAD + lane32 * 4);
        const f4 v3 = nt_load4(Vbase + (size_t)(s + 3) * DHEAD + lane32 * 4);
        const float p0 = __expf(sc[s    ] - m);    // uniform within group
        const float p1 = __expf(sc[s + 1] - m);
        const float p2 = __expf(sc[s + 2] - m);
        const float p3 = __expf(sc[s + 3] - m);
        acc += p0 * v0 + p1 * v1 + p2 * v2 + p3 * v3;
        lsum += (p0 + p1) + (p2 + p3);
    }
    *((f4*)accs[grp] + lane32) = acc;
    if (lane32 == 0) redl[grp] = lsum;   // lsum uniform within group
    __syncthreads();

    float* P = part + ((size_t)bh * nsplit + split) * PSTRIDE;
    if (tid < DHEAD) {
        float a = 0.f;
        #pragma unroll
        for (int g = 0; g < 8; ++g) a += accs[g][tid];
        P[tid] = a;
    }
    if (tid == 0) {
        P[DHEAD] = m;
        P[DHEAD + 1] = ((redl[0] + redl[1]) + (redl[2] + redl[3]))
                     + ((redl[4] + redl[5]) + (redl[6] + redl[7]));
    }
}

// ---------------------------------------------------------------------------
// Kernel 2: combine splits (log-sum-exp merge), write attn as [B, H*D].
// ---------------------------------------------------------------------------
__global__ __launch_bounds__(DHEAD) void attn_combine(
    const float* __restrict__ part, float* __restrict__ attn,
    int nsplit)
{
    const int bh  = blockIdx.x;
    const int tid = threadIdx.x;        // 0..127
    const float* P = part + (size_t)bh * nsplit * PSTRIDE;

    float m = -INFINITY;
    for (int s = 0; s < nsplit; ++s)
        m = fmaxf(m, P[s * PSTRIDE + DHEAD]);

    float l = 0.f, a = 0.f;
    for (int s = 0; s < nsplit; ++s) {
        const float w = __expf(P[s * PSTRIDE + DHEAD] - m);
        l += P[s * PSTRIDE + DHEAD + 1] * w;
        a += P[s * PSTRIDE + tid] * w;
    }
    attn[(size_t)bh * DHEAD + tid] = a / l;   // bh*128 == b*(H*D) + h*D
}

// ---------------------------------------------------------------------------
// Kernel 3: out[b][j] = bias[j] + attn[b,:] . W[j,:]   (torch Linear: x @ W^T)
// NJ=8 columns per block: W rows streamed once via NT loads (64 MB total),
// attn L2 reads amortized 8x.
// ---------------------------------------------------------------------------
__global__ __launch_bounds__(TPB) void out_proj(
    const float* __restrict__ attn, const float* __restrict__ W,
    const float* __restrict__ bias, float* __restrict__ out, int HD)
{
    const int j0  = blockIdx.x * NJ;
    const int tid = threadIdx.x;
    const int nv  = HD >> 2;             // 1024 float4s per row
    const f4* attn4 = (const f4*)attn;

    float acc[NJ][NB];
    #pragma unroll
    for (int c = 0; c < NJ; ++c)
        #pragma unroll
        for (int b = 0; b < NB; ++b) acc[c][b] = 0.f;

    for (int i = tid; i < nv; i += TPB) {           // 4 iterations
        f4 w4[NJ];
        #pragma unroll
        for (int c = 0; c < NJ; ++c)
            w4[c] = nt_load4(W + (size_t)(j0 + c) * HD + i * 4);
        #pragma unroll
        for (int b = 0; b < NB; ++b) {
            const f4 a4 = attn4[(size_t)b * nv + i];
            #pragma unroll
            for (int c = 0; c < NJ; ++c) {
                acc[c][b] += w4[c].x * a4.x + w4[c].y * a4.y
                           + w4[c].z * a4.z + w4[c].w * a4.w;
            }
        }
    }

    // wave-level reduce (64 lanes), then cross-wave via LDS
    #pragma unroll
    for (int c = 0; c < NJ; ++c)
        #pragma unroll
        for (int b = 0; b < NB; ++b)
            #pragma unroll
            for (int off = 32; off > 0; off >>= 1)
                acc[c][b] += __shfl_xor(acc[c][b], off);

    __shared__ float red[4][NJ][NB];
    if ((tid & 63) == 0) {
        #pragma unroll
        for (int c = 0; c < NJ; ++c)
            #pragma unroll
            for (int b = 0; b < NB; ++b) red[tid >> 6][c][b] = acc[c][b];
    }
    __syncthreads();
    if (tid < NJ * NB) {                 // 64 threads
        const int c = tid >> 3, b = tid & 7;
        const float r = red[0][c][b] + red[1][c][b] + red[2][c][b] + red[3][c][b];
        out[(size_t)b * HD + (j0 + c)] = r + bias[j0 + c];
    }
}

// ---------------------------------------------------------------------------
extern "C" void kernel_launch(void* const* d_in, const int* in_sizes, int n_in,
                              void* d_out, int out_size, void* d_ws, size_t ws_size,
                              hipStream_t stream)
{
    const float* q    = (const float*)d_in[0];
    const float* kc   = (const float*)d_in[1];
    const float* vc   = (const float*)d_in[2];
    const float* W    = (const float*)d_in[3];
    const float* bias = (const float*)d_in[4];
    float* out = (float*)d_out;

    const int HD = in_sizes[4];                 // H*D = 4096
    const int S  = in_sizes[1] / in_sizes[0];   // 8192
    const int BH = in_sizes[0] / DHEAD;         // B*H = 256
    const int nsplit = S / CHUNK;               // 8

    float* part = (float*)d_ws;                              // BH*nsplit*130 floats
    float* attn = part + (size_t)BH * nsplit * PSTRIDE;      // B*HD floats (128 KB)

    attn_partial<<<dim3(BH, nsplit), TPB, 0, stream>>>(q, kc, vc, part, S, nsplit);
    attn_combine<<<BH, DHEAD, 0, stream>>>(part, attn, nsplit);
    out_proj<<<HD / NJ, TPB, 0, stream>>>(attn, W, bias, out, HD);
}